// Round 12
// baseline (67.017 us; speedup 1.0000x reference)
//
#include <hip/hip_runtime.h>
#include <math.h>

// Net: 4 layers of out = 0.8*(x@W^T) + 0.2*max_i(W[o,i]*x[b,i]) + b
// B=1024, dims 256 -> 512 -> 512 -> 512 -> 1. All fp32.
//
// R12: occupancy experiment. R7/R8/R11 all ran 1 block/CU (2 waves/SIMD)
// and all sit at 57-62us with ~42% VALU idle; R11 falsified the LDS-pipe
// theory, R8 falsified W-prefetch depth. Hypothesis: exposed latency at
// minimal TLP. This round: R7's exact microtile (G=1, packed fp32+max3,
// group-of-4 named-register prefetch) but 2 ROWS/block, 512 blocks
// -> 2 blocks/CU = 4 waves/SIMD. W panel L2 traffic doubles (~28 TB/s,
// under ceiling); LDS 8.4KB/block. No other changes.

#define NT   512
#define ROWS 2

typedef float v2f __attribute__((ext_vector_type(2)));
typedef float v4f __attribute__((ext_vector_type(4)));

#define V2LO(v) __builtin_shufflevector((v), (v), 0, 1)
#define V2HI(v) __builtin_shufflevector((v), (v), 2, 3)

// ws layout in float4 units
#define WT1_OFF 0
#define WT2_OFF 33280    // 32768 + 512 pad
#define WT3_OFF 99328    // 33280 + 65536 + 512 pad

__global__ __launch_bounds__(256) void transpose_all(
    const float* __restrict__ W1, const float* __restrict__ W2,
    const float* __restrict__ W3, float4* __restrict__ ws)
{
    const int tid = blockIdx.x * 256 + threadIdx.x;   // 0 .. 163839
    const float* W;
    float4* WT;
    int o, k4, K;
    if (tid < 32768) {                    // W1: O=512, K=256, K4=64
        W = W1; WT = ws + WT1_OFF; K = 256;
        o = tid >> 6; k4 = tid & 63;
    } else if (tid < 98304) {             // W2: O=512, K=512, K4=128
        const int idx = tid - 32768;
        W = W2; WT = ws + WT2_OFF; K = 512;
        o = idx >> 7; k4 = idx & 127;
    } else {                              // W3: O=512, K=512, K4=128
        const int idx = tid - 98304;
        W = W3; WT = ws + WT3_OFF; K = 512;
        o = idx >> 7; k4 = idx & 127;
    }
    float4 v = *(const float4*)&W[(size_t)o * K + 4 * k4];
    WT[(size_t)k4 * 512 + o] = v;
}

// one k4 (4 k-elems) for 2 rows: 12 VALU (4 pk_mul + 4 pk_add + 4 max3)
#define K4_STEP(wv, H0, H1)                                                 \
    {                                                                       \
        const v2f wLo = V2LO(wv), wHi = V2HI(wv);                           \
        { v2f pL = V2LO(H0) * wLo, pH = V2HI(H0) * wHi;                     \
          sL0 += pL; sH0 += pH;                                             \
          mL0 = fmaxf(fmaxf(mL0, pL[0]), pL[1]);                            \
          mH0 = fmaxf(fmaxf(mH0, pH[0]), pH[1]); }                          \
        { v2f pL = V2LO(H1) * wLo, pH = V2HI(H1) * wHi;                     \
          sL1 += pL; sH1 += pH;                                             \
          mL1 = fmaxf(fmaxf(mL1, pL[0]), pL[1]);                            \
          mH1 = fmaxf(fmaxf(mH1, pH[0]), pH[1]); }                          \
    }

// Thread t owns output neuron o=t for 2 rows. W from coalesced panels,
// h wave-uniform LDS broadcasts. Group-of-4 named-register prefetch.
__device__ __forceinline__ void layer_bcast(
    const float (*__restrict__ hin)[512],
    float (*__restrict__ hout)[512],
    const v4f* __restrict__ WT,    // [K4][512]
    const float* __restrict__ bias,
    int K4, int t)
{
    v2f sL0 = (v2f)0.f, sH0 = (v2f)0.f, sL1 = (v2f)0.f, sH1 = (v2f)0.f;
    float mL0 = -INFINITY, mH0 = -INFINITY, mL1 = -INFINITY, mH1 = -INFINITY;

    const v4f* wp = WT + t;
    const v4f* h0p = (const v4f*)hin[0];
    const v4f* h1p = (const v4f*)hin[1];

    v4f w0 = wp[0], w1 = wp[512], w2 = wp[1024], w3 = wp[1536];
    v4f h00 = h0p[0], h01 = h1p[0];
    v4f h10 = h0p[1], h11 = h1p[1];
    v4f h20 = h0p[2], h21 = h1p[2];
    v4f h30 = h0p[3], h31 = h1p[3];

    #pragma unroll 1
    for (int kg = 0; kg + 4 < K4; kg += 4) {
        K4_STEP(w0, h00, h01);
        w0 = wp[(size_t)(kg + 4) * 512];
        h00 = h0p[kg + 4]; h01 = h1p[kg + 4];
        K4_STEP(w1, h10, h11);
        w1 = wp[(size_t)(kg + 5) * 512];
        h10 = h0p[kg + 5]; h11 = h1p[kg + 5];
        K4_STEP(w2, h20, h21);
        w2 = wp[(size_t)(kg + 6) * 512];
        h20 = h0p[kg + 6]; h21 = h1p[kg + 6];
        K4_STEP(w3, h30, h31);
        w3 = wp[(size_t)(kg + 7) * 512];
        h30 = h0p[kg + 7]; h31 = h1p[kg + 7];
    }
    // peeled tail (last 4 k4), no refills
    K4_STEP(w0, h00, h01);
    K4_STEP(w1, h10, h11);
    K4_STEP(w2, h20, h21);
    K4_STEP(w3, h30, h31);

    const float bo = bias[t];
    {
        v2f sv = sL0 + sH0;
        hout[0][t] = fmaf(0.2f, fmaxf(mL0, mH0), fmaf(0.8f, sv[0] + sv[1], bo));
    }
    {
        v2f sv = sL1 + sH1;
        hout[1][t] = fmaf(0.2f, fmaxf(mL1, mH1), fmaf(0.8f, sv[0] + sv[1], bo));
    }
}

__global__ __launch_bounds__(NT) void net_fused(
    const float* __restrict__ x,
    const v4f* __restrict__ WT1, const float* __restrict__ b1,
    const v4f* __restrict__ WT2, const float* __restrict__ b2,
    const v4f* __restrict__ WT3, const float* __restrict__ b3,
    const float* __restrict__ W4, const float* __restrict__ b4,
    float* __restrict__ out)
{
    __shared__ __align__(16) float ha[ROWS][512];
    __shared__ __align__(16) float hb[ROWS][512];
    __shared__ float red_s[8][ROWS];
    __shared__ float red_m[8][ROWS];

    const int t = threadIdx.x;
    const int row0 = blockIdx.x * ROWS;

    // stage x rows (2 x 256) into ha: one float per thread
    {
        const int r = t >> 8;
        const int c = t & 255;
        ha[r][c] = x[(size_t)(row0 + r) * 256 + c];
    }
    __syncthreads();

    layer_bcast(ha, hb, WT1, b1, 64,  t);   // x  -> h1
    __syncthreads();
    layer_bcast(hb, ha, WT2, b2, 128, t);   // h1 -> h2
    __syncthreads();
    layer_bcast(ha, hb, WT3, b3, 128, t);   // h2 -> h3
    __syncthreads();

    // ---- layer 4: O=1 ----
    const float w4 = W4[t];
    float ps0, ps1, pm0, pm1;
    {
        float p0 = w4 * hb[0][t]; ps0 = p0; pm0 = p0;
        float p1 = w4 * hb[1][t]; ps1 = p1; pm1 = p1;
    }
    #pragma unroll
    for (int off = 32; off; off >>= 1) {
        ps0 += __shfl_xor(ps0, off, 64);
        pm0 = fmaxf(pm0, __shfl_xor(pm0, off, 64));
        ps1 += __shfl_xor(ps1, off, 64);
        pm1 = fmaxf(pm1, __shfl_xor(pm1, off, 64));
    }
    const int lane = t & 63;
    const int wave = t >> 6;
    if (lane == 0) {
        red_s[wave][0] = ps0; red_m[wave][0] = pm0;
        red_s[wave][1] = ps1; red_m[wave][1] = pm1;
    }
    __syncthreads();

    if (t < ROWS) {
        float s = red_s[0][t];
        float m = red_m[0][t];
        #pragma unroll
        for (int w = 1; w < 8; ++w) {
            s += red_s[w][t];
            m = fmaxf(m, red_m[w][t]);
        }
        out[row0 + t] = fmaf(0.2f, m, fmaf(0.8f, s, b4[0]));
    }
}

extern "C" void kernel_launch(void* const* d_in, const int* in_sizes, int n_in,
                              void* d_out, int out_size, void* d_ws, size_t ws_size,
                              hipStream_t stream)
{
    const float* x  = (const float*)d_in[0];
    const float* W1 = (const float*)d_in[1];
    const float* b1 = (const float*)d_in[2];
    const float* W2 = (const float*)d_in[3];
    const float* b2 = (const float*)d_in[4];
    const float* W3 = (const float*)d_in[5];
    const float* b3 = (const float*)d_in[6];
    const float* W4 = (const float*)d_in[7];
    const float* b4 = (const float*)d_in[8];

    float4* ws4 = (float4*)d_ws;

    transpose_all<<<640, 256, 0, stream>>>(W1, W2, W3, ws4);

    net_fused<<<512, NT, 0, stream>>>(
        x,
        (const v4f*)(ws4 + WT1_OFF), b1,
        (const v4f*)(ws4 + WT2_OFF), b2,
        (const v4f*)(ws4 + WT3_OFF), b3,
        W4, b4,
        (float*)d_out);
}

// Round 13
// 66.842 us; speedup vs baseline: 1.0026x; 1.0026x over previous
//
#include <hip/hip_runtime.h>
#include <math.h>

// Net: 4 layers of out = 0.8*(x@W^T) + 0.2*max_i(W[o,i]*x[b,i]) + b
// B=1024, dims 256 -> 512 -> 512 -> 512 -> 1. All fp32.
//
// R13 = R7 (best: 57us kernel / 58.6 total) with exactly two deltas:
//  1. layer_bcast templated on K4 (compile-time trip count -> full
//     strength reduction of W/h address IVs, folded guards)
//  2. #pragma unroll 2 on the kg loop (compiler-managed IV merging)
// Everything else byte-identical to R7: fused single kernel, coalesced
// pre-transposed W panels, packed fp32 (v_pk_mul/v_pk_add) + v_max3,
// group-of-4 named-register prefetch, h as wave-uniform LDS broadcasts.

#define NT   512
#define ROWS 4

typedef float v2f __attribute__((ext_vector_type(2)));

// ws layout in float4 units
#define WT1_OFF 0
#define WT2_OFF 33280    // 32768 + 512 pad
#define WT3_OFF 99328    // 33280 + 65536 + 512 pad

__global__ __launch_bounds__(256) void transpose_all(
    const float* __restrict__ W1, const float* __restrict__ W2,
    const float* __restrict__ W3, float4* __restrict__ ws)
{
    const int tid = blockIdx.x * 256 + threadIdx.x;   // 0 .. 163839
    const float* W;
    float4* WT;
    int o, k4, K;
    if (tid < 32768) {                    // W1: O=512, K=256, K4=64
        W = W1; WT = ws + WT1_OFF; K = 256;
        o = tid >> 6; k4 = tid & 63;
    } else if (tid < 98304) {             // W2: O=512, K=512, K4=128
        const int idx = tid - 32768;
        W = W2; WT = ws + WT2_OFF; K = 512;
        o = idx >> 7; k4 = idx & 127;
    } else {                              // W3: O=512, K=512, K4=128
        const int idx = tid - 98304;
        W = W3; WT = ws + WT3_OFF; K = 512;
        o = idx >> 7; k4 = idx & 127;
    }
    float4 v = *(const float4*)&W[(size_t)o * K + 4 * k4];
    WT[(size_t)k4 * 512 + o] = v;
}

// One layer: thread t owns output neuron o=t for ROWS batch rows.
// W from global (coalesced panel), h from LDS (wave-uniform broadcast).
template<int K4>
__device__ __forceinline__ void layer_bcast(
    const float (*__restrict__ hin)[512],
    float (*__restrict__ hout)[512],
    const float4* __restrict__ WT,    // [K4][512]
    const float* __restrict__ bias,
    int t)
{
    v2f sA[ROWS], sB[ROWS];
    float mA[ROWS], mB[ROWS];
    #pragma unroll
    for (int r = 0; r < ROWS; ++r) {
        sA[r] = (v2f)0.f; sB[r] = (v2f)0.f;
        mA[r] = -INFINITY; mB[r] = -INFINITY;
    }

    const float4* wp = WT + t;
    float4 w0 = wp[0];
    float4 w1 = wp[512];
    float4 w2 = wp[1024];
    float4 w3 = wp[1536];

    #pragma unroll 2
    for (int kg = 0; kg < K4; kg += 4) {
        float4 n0 = w0, n1 = w1, n2 = w2, n3 = w3;
        if (kg + 4 < K4) {                 // uniform (scalar) branch
            const float4* q = wp + (size_t)(kg + 4) * 512;
            n0 = q[0];
            n1 = q[512];
            n2 = q[1024];
            n3 = q[1536];
        }
        #pragma unroll
        for (int j = 0; j < 4; ++j) {
            const float4 w = (j == 0) ? w0 : (j == 1) ? w1 : (j == 2) ? w2 : w3;
            const int k = (kg + j) * 4;
            v2f w01; w01[0] = w.x; w01[1] = w.y;
            v2f w23; w23[0] = w.z; w23[1] = w.w;
            #pragma unroll
            for (int r = 0; r < ROWS; ++r) {
                float4 h = *(const float4*)&hin[r][k];   // wave-uniform bcast
                v2f h01; h01[0] = h.x; h01[1] = h.y;
                v2f h23; h23[0] = h.z; h23[1] = h.w;
                v2f p01 = w01 * h01;                     // v_pk_mul_f32
                v2f p23 = w23 * h23;
                sA[r] += p01;                            // v_pk_add_f32
                sB[r] += p23;
                mA[r] = fmaxf(fmaxf(mA[r], p01[0]), p01[1]);   // v_max3_f32
                mB[r] = fmaxf(fmaxf(mB[r], p23[0]), p23[1]);
            }
        }
        w0 = n0; w1 = n1; w2 = n2; w3 = n3;
    }

    const float bo = bias[t];
    #pragma unroll
    for (int r = 0; r < ROWS; ++r) {
        v2f sv = sA[r] + sB[r];
        float s = sv[0] + sv[1];
        float m = fmaxf(mA[r], mB[r]);
        hout[r][t] = fmaf(0.2f, m, fmaf(0.8f, s, bo));
    }
}

__global__ __launch_bounds__(NT) void net_fused(
    const float* __restrict__ x,
    const float4* __restrict__ WT1, const float* __restrict__ b1,
    const float4* __restrict__ WT2, const float* __restrict__ b2,
    const float4* __restrict__ WT3, const float* __restrict__ b3,
    const float* __restrict__ W4,   const float* __restrict__ b4,
    float* __restrict__ out)
{
    __shared__ __align__(16) float ha[ROWS][512];
    __shared__ __align__(16) float hb[ROWS][512];
    __shared__ float red_s[8][ROWS];
    __shared__ float red_m[8][ROWS];

    const int t = threadIdx.x;
    const int row0 = blockIdx.x * ROWS;

    // stage x rows (4 x 256) into ha: one float2 per thread
    {
        const int r = t >> 7;
        const int c = (t & 127) * 2;
        float2 v = *(const float2*)&x[(size_t)(row0 + r) * 256 + c];
        ha[r][c]     = v.x;
        ha[r][c + 1] = v.y;
    }
    __syncthreads();

    layer_bcast<64> (ha, hb, WT1, b1, t);   // x  -> h1
    __syncthreads();
    layer_bcast<128>(hb, ha, WT2, b2, t);   // h1 -> h2
    __syncthreads();
    layer_bcast<128>(ha, hb, WT3, b3, t);   // h2 -> h3
    __syncthreads();

    // ---- layer 4: O=1 ----
    const float w4 = W4[t];
    float ps[ROWS], pm[ROWS];
    #pragma unroll
    for (int r = 0; r < ROWS; ++r) {
        float p = w4 * hb[r][t];
        ps[r] = p;
        pm[r] = p;
    }
    #pragma unroll
    for (int off = 32; off; off >>= 1) {
        #pragma unroll
        for (int r = 0; r < ROWS; ++r) {
            ps[r] += __shfl_xor(ps[r], off, 64);
            pm[r] = fmaxf(pm[r], __shfl_xor(pm[r], off, 64));
        }
    }
    const int lane = t & 63;
    const int wave = t >> 6;
    if (lane == 0) {
        #pragma unroll
        for (int r = 0; r < ROWS; ++r) {
            red_s[wave][r] = ps[r];
            red_m[wave][r] = pm[r];
        }
    }
    __syncthreads();

    if (t < ROWS) {
        float s = red_s[0][t];
        float m = red_m[0][t];
        #pragma unroll
        for (int w = 1; w < 8; ++w) {
            s += red_s[w][t];
            m = fmaxf(m, red_m[w][t]);
        }
        out[row0 + t] = fmaf(0.2f, m, fmaf(0.8f, s, b4[0]));
    }
}

extern "C" void kernel_launch(void* const* d_in, const int* in_sizes, int n_in,
                              void* d_out, int out_size, void* d_ws, size_t ws_size,
                              hipStream_t stream)
{
    const float* x  = (const float*)d_in[0];
    const float* W1 = (const float*)d_in[1];
    const float* b1 = (const float*)d_in[2];
    const float* W2 = (const float*)d_in[3];
    const float* b2 = (const float*)d_in[4];
    const float* W3 = (const float*)d_in[5];
    const float* b3 = (const float*)d_in[6];
    const float* W4 = (const float*)d_in[7];
    const float* b4 = (const float*)d_in[8];

    float4* ws4 = (float4*)d_ws;

    transpose_all<<<640, 256, 0, stream>>>(W1, W2, W3, ws4);

    net_fused<<<256, NT, 0, stream>>>(
        x,
        ws4 + WT1_OFF, b1,
        ws4 + WT2_OFF, b2,
        ws4 + WT3_OFF, b3,
        W4, b4,
        (float*)d_out);
}

// Round 14
// 58.801 us; speedup vs baseline: 1.1397x; 1.1367x over previous
//
#include <hip/hip_runtime.h>
#include <math.h>

// Net: 4 layers of out = 0.8*(x@W^T) + 0.2*max_i(W[o,i]*x[b,i]) + b
// B=1024, dims 256 -> 512 -> 512 -> 512 -> 1. All fp32.
//
// FINAL = R7 (best measured: 57us kernel / 58.6us total).
// Structure: fully fused single kernel (block owns 4 batch rows through all
// layers, h ping-pongs in LDS); W pre-transposed to coalesced [k4][o]
// float4 panels in d_ws (one wave-instr = 64 consecutive float4s); h read
// as wave-uniform LDS float4 broadcasts (bank-conflict-free); packed fp32
// arithmetic (v_pk_mul_f32 / v_pk_add_f32) + v_max3_f32 = 1.5 VALU
// instr/product (the packed-VALU floor for mul+add+max); group-of-4
// named-register W prefetch (no runtime-indexed register arrays).
//
// Falsified levers (kept for the record): deeper prefetch (R8 +6us),
// 4x fewer LDS broadcasts (R11 +5us), 2x TLP (R12 flat), scalar-pipe h
// (R10 2x), compile-time K4 + unroll 2 (R13 +8us).

#define NT   512
#define ROWS 4

typedef float v2f __attribute__((ext_vector_type(2)));

// ws layout in float4 units
#define WT1_OFF 0
#define WT2_OFF 33280    // 32768 + 512 pad
#define WT3_OFF 99328    // 33280 + 65536 + 512 pad

__global__ __launch_bounds__(256) void transpose_all(
    const float* __restrict__ W1, const float* __restrict__ W2,
    const float* __restrict__ W3, float4* __restrict__ ws)
{
    const int tid = blockIdx.x * 256 + threadIdx.x;   // 0 .. 163839
    const float* W;
    float4* WT;
    int o, k4, K;
    if (tid < 32768) {                    // W1: O=512, K=256, K4=64
        W = W1; WT = ws + WT1_OFF; K = 256;
        o = tid >> 6; k4 = tid & 63;
    } else if (tid < 98304) {             // W2: O=512, K=512, K4=128
        const int idx = tid - 32768;
        W = W2; WT = ws + WT2_OFF; K = 512;
        o = idx >> 7; k4 = idx & 127;
    } else {                              // W3: O=512, K=512, K4=128
        const int idx = tid - 98304;
        W = W3; WT = ws + WT3_OFF; K = 512;
        o = idx >> 7; k4 = idx & 127;
    }
    float4 v = *(const float4*)&W[(size_t)o * K + 4 * k4];
    WT[(size_t)k4 * 512 + o] = v;
}

// One layer: thread t owns output neuron o=t for ROWS batch rows.
// W from global (coalesced panel), h from LDS (wave-uniform broadcast).
__device__ __forceinline__ void layer_bcast(
    const float (*__restrict__ hin)[512],
    float (*__restrict__ hout)[512],
    const float4* __restrict__ WT,    // [K4][512]
    const float* __restrict__ bias,
    int K4, int t)
{
    v2f sA[ROWS], sB[ROWS];
    float mA[ROWS], mB[ROWS];
    #pragma unroll
    for (int r = 0; r < ROWS; ++r) {
        sA[r] = (v2f)0.f; sB[r] = (v2f)0.f;
        mA[r] = -INFINITY; mB[r] = -INFINITY;
    }

    const float4* wp = WT + t;
    float4 w0 = wp[0];
    float4 w1 = wp[512];
    float4 w2 = wp[1024];
    float4 w3 = wp[1536];

    for (int kg = 0; kg < K4; kg += 4) {
        float4 n0 = w0, n1 = w1, n2 = w2, n3 = w3;
        if (kg + 4 < K4) {                 // uniform (scalar) branch
            const float4* q = wp + (size_t)(kg + 4) * 512;
            n0 = q[0];
            n1 = q[512];
            n2 = q[1024];
            n3 = q[1536];
        }
        #pragma unroll
        for (int j = 0; j < 4; ++j) {
            const float4 w = (j == 0) ? w0 : (j == 1) ? w1 : (j == 2) ? w2 : w3;
            const int k = (kg + j) * 4;
            v2f w01; w01[0] = w.x; w01[1] = w.y;
            v2f w23; w23[0] = w.z; w23[1] = w.w;
            #pragma unroll
            for (int r = 0; r < ROWS; ++r) {
                float4 h = *(const float4*)&hin[r][k];   // wave-uniform bcast
                v2f h01; h01[0] = h.x; h01[1] = h.y;
                v2f h23; h23[0] = h.z; h23[1] = h.w;
                v2f p01 = w01 * h01;                     // v_pk_mul_f32
                v2f p23 = w23 * h23;
                sA[r] += p01;                            // v_pk_add_f32
                sB[r] += p23;
                mA[r] = fmaxf(fmaxf(mA[r], p01[0]), p01[1]);   // v_max3_f32
                mB[r] = fmaxf(fmaxf(mB[r], p23[0]), p23[1]);
            }
        }
        w0 = n0; w1 = n1; w2 = n2; w3 = n3;
    }

    const float bo = bias[t];
    #pragma unroll
    for (int r = 0; r < ROWS; ++r) {
        v2f sv = sA[r] + sB[r];
        float s = sv[0] + sv[1];
        float m = fmaxf(mA[r], mB[r]);
        hout[r][t] = fmaf(0.2f, m, fmaf(0.8f, s, bo));
    }
}

__global__ __launch_bounds__(NT) void net_fused(
    const float* __restrict__ x,
    const float4* __restrict__ WT1, const float* __restrict__ b1,
    const float4* __restrict__ WT2, const float* __restrict__ b2,
    const float4* __restrict__ WT3, const float* __restrict__ b3,
    const float* __restrict__ W4,   const float* __restrict__ b4,
    float* __restrict__ out)
{
    __shared__ __align__(16) float ha[ROWS][512];
    __shared__ __align__(16) float hb[ROWS][512];
    __shared__ float red_s[8][ROWS];
    __shared__ float red_m[8][ROWS];

    const int t = threadIdx.x;
    const int row0 = blockIdx.x * ROWS;

    // stage x rows (4 x 256) into ha: one float2 per thread
    {
        const int r = t >> 7;
        const int c = (t & 127) * 2;
        float2 v = *(const float2*)&x[(size_t)(row0 + r) * 256 + c];
        ha[r][c]     = v.x;
        ha[r][c + 1] = v.y;
    }
    __syncthreads();

    layer_bcast(ha, hb, WT1, b1, 64,  t);   // x  -> h1
    __syncthreads();
    layer_bcast(hb, ha, WT2, b2, 128, t);   // h1 -> h2
    __syncthreads();
    layer_bcast(ha, hb, WT3, b3, 128, t);   // h2 -> h3
    __syncthreads();

    // ---- layer 4: O=1 ----
    const float w4 = W4[t];
    float ps[ROWS], pm[ROWS];
    #pragma unroll
    for (int r = 0; r < ROWS; ++r) {
        float p = w4 * hb[r][t];
        ps[r] = p;
        pm[r] = p;
    }
    #pragma unroll
    for (int off = 32; off; off >>= 1) {
        #pragma unroll
        for (int r = 0; r < ROWS; ++r) {
            ps[r] += __shfl_xor(ps[r], off, 64);
            pm[r] = fmaxf(pm[r], __shfl_xor(pm[r], off, 64));
        }
    }
    const int lane = t & 63;
    const int wave = t >> 6;
    if (lane == 0) {
        #pragma unroll
        for (int r = 0; r < ROWS; ++r) {
            red_s[wave][r] = ps[r];
            red_m[wave][r] = pm[r];
        }
    }
    __syncthreads();

    if (t < ROWS) {
        float s = red_s[0][t];
        float m = red_m[0][t];
        #pragma unroll
        for (int w = 1; w < 8; ++w) {
            s += red_s[w][t];
            m = fmaxf(m, red_m[w][t]);
        }
        out[row0 + t] = fmaf(0.2f, m, fmaf(0.8f, s, b4[0]));
    }
}

extern "C" void kernel_launch(void* const* d_in, const int* in_sizes, int n_in,
                              void* d_out, int out_size, void* d_ws, size_t ws_size,
                              hipStream_t stream)
{
    const float* x  = (const float*)d_in[0];
    const float* W1 = (const float*)d_in[1];
    const float* b1 = (const float*)d_in[2];
    const float* W2 = (const float*)d_in[3];
    const float* b2 = (const float*)d_in[4];
    const float* W3 = (const float*)d_in[5];
    const float* b3 = (const float*)d_in[6];
    const float* W4 = (const float*)d_in[7];
    const float* b4 = (const float*)d_in[8];

    float4* ws4 = (float4*)d_ws;

    transpose_all<<<640, 256, 0, stream>>>(W1, W2, W3, ws4);

    net_fused<<<256, NT, 0, stream>>>(
        x,
        ws4 + WT1_OFF, b1,
        ws4 + WT2_OFF, b2,
        ws4 + WT3_OFF, b3,
        W4, b4,
        (float*)d_out);
}